// Round 9
// baseline (192.896 us; speedup 1.0000x reference)
//
#include <hip/hip_runtime.h>
#include <hip/hip_bf16.h>
#include <math.h>

#define HW 9216      // 96*96
#define C2 64
#define NJC 36       // j-chunk count (grid.y)
#define JTILE 32     // j-tile per lane = 32 accs as 8 x v4
#define EPSN 1e-8f

typedef float v4 __attribute__((ext_vector_type(4)));

// ---------------- kernel 1: compaction (256 threads, shuffle scan) --------
// ilist = positions with mask>=1 (flagged i), jlist = positions with mask<1
__global__ void compact_kernel(const int* __restrict__ mask, int* __restrict__ ilist,
                               int* __restrict__ jlist, int* __restrict__ counts) {
    int t = threadIdx.x;                 // 0..255, each owns 36 consecutive positions
    int base = t * 36;
    unsigned long long fl = 0ull; int cnt = 0;
#pragma unroll
    for (int k = 0; k < 36; k++) {
        int f = (mask[base + k] >= 1) ? 1 : 0;
        fl |= (unsigned long long)f << k;
        cnt += f;
    }
    int lane = t & 63, wave = t >> 6;
    int v = cnt;
#pragma unroll
    for (int off = 1; off < 64; off <<= 1) {
        int u = __shfl_up(v, off, 64);
        if (lane >= off) v += u;
    }
    __shared__ int wsum[4];
    if (lane == 63) wsum[wave] = v;
    __syncthreads();
    int woff = 0;
#pragma unroll
    for (int w = 0; w < 4; w++) if (w < wave) woff += wsum[w];
    int incl = v + woff;
    int excl = incl - cnt;
    int posF = excl, posU = base - excl;
#pragma unroll
    for (int k = 0; k < 36; k++) {
        int p = base + k;
        if ((fl >> k) & 1ull) ilist[posF++] = p; else jlist[posU++] = p;
    }
    if (t == 255) { counts[0] = incl; counts[1] = HW - incl; }
}

// ---------------- kernel 2: build transposed compacted A and B ------------
// amatT[b][c][ci] = lat[b][c][ilist[ci]]                    (unnormalized)
// bmatT[b][c][jj] = lat[b][c][jlist[jj]] / max(||lat_j||,eps)
// zero-padded to HW columns (tail lanes/tiles read benign zeros). Zeroes amax.
__global__ void buildab_kernel(const float* __restrict__ x, const int* __restrict__ ilist,
                               const int* __restrict__ jlist, const int* __restrict__ counts,
                               float* __restrict__ amatT, float* __restrict__ bmatT,
                               unsigned long long* __restrict__ amax) {
    int t = blockIdx.x * blockDim.x + threadIdx.x;   // 0 .. 4*HW-1
    if (t >= 4 * HW) return;
    if (t < 2 * HW) amax[t] = 0ull;                  // ws is poisoned 0xAA pre-launch
    int kind = t / (2 * HW);                         // 0 = A, 1 = B
    int r = t - kind * 2 * HW;
    int b = r / HW, p = r - b * HW;
    int n = kind ? counts[1] : counts[0];
    float v[C2];
    if (p < n) {
        int src = kind ? jlist[p] : ilist[p];
        const float* xl = x + (size_t)(b * 128 + 64) * HW + src;
        float ss = 0.f;
#pragma unroll
        for (int c = 0; c < C2; c++) { float w = xl[(size_t)c * HW]; v[c] = w; ss = fmaf(w, w, ss); }
        if (kind) {
            float inv = 1.0f / fmaxf(sqrtf(ss), EPSN);
#pragma unroll
            for (int c = 0; c < C2; c++) v[c] *= inv;
        }
    } else {
#pragma unroll
        for (int c = 0; c < C2; c++) v[c] = 0.f;
    }
    float* d = (kind ? bmatT : amatT) + (size_t)b * C2 * HW + p;
#pragma unroll
    for (int c = 0; c < C2; c++) d[(size_t)c * HW] = v[c];
}

// ordered-float mapping: monotone bijection float -> uint32 under unsigned compare
__device__ __forceinline__ unsigned int ordf(float f) {
    unsigned int u = __float_as_uint(f);
    return (u & 0x80000000u) ? ~u : (u | 0x80000000u);
}

// ---------------- kernel 3: broadcast-B GEMM + argmax ---------------------
// Lane owns one ci and a 32-wide j-tile as 8 x v4 accumulators (the phrasing
// that survived regalloc in R8). B j-tile (64c x 32j = 8 KB) staged in LDS,
// read with WAVE-UNIFORM ds_read_b128 -> broadcast, conflict-free, ~1-4 cyc
// (vs per-lane reads that made R8 LDS-BW-bound). Per c: 1 coalesced VMEM
// dword (amatT, zero-padded -> no clamps) + 8 uniform LDS reads + 32 v_fmac.
// First-max tie-break: ascending jb, ascending k, strict >, packed-u64
// atomicMax (key = ord(val)<<32 | ~jj).
__global__ __launch_bounds__(256, 4) void gemm_argmax_kernel(
    const float* __restrict__ amatT, const float* __restrict__ bmatT,
    const int* __restrict__ ilist, const int* __restrict__ counts,
    unsigned long long* __restrict__ amax)
{
    __shared__ float Bs[C2][JTILE];                  // 8 KB
    int b = blockIdx.z;
    int sc = blockIdx.y;
    int ci = blockIdx.x * 256 + threadIdx.x;
    int ni = counts[0], nj = counts[1];
    if (blockIdx.x * 256 >= ni) return;              // uniform dead-block exit
    int t = threadIdx.x;
    const float* Ab = amatT + (size_t)b * C2 * HW;
    const float* Bb = bmatT + (size_t)b * C2 * HW;
    int chunk = (((nj + NJC - 1) / NJC) + 31) & ~31; // mult of 32
    int j0 = sc * chunk;
    int j1 = min(j0 + chunk, nj);
    float best = -INFINITY; int bestjj = -1;
    for (int jb = j0; jb < j1; jb += JTILE) {
        __syncthreads();                             // prev-tile readers done
        // stage 8 KB B-tile: 2 x v4 per thread, coalesced (jb mult of 32 -> 128B rows)
#pragma unroll
        for (int q = 0; q < 2; q++) {
            int slot = q * 256 + t;                  // 0..511 v4 slots
            int c = slot >> 3, col4 = (slot & 7) * 4;
            *(v4*)&Bs[c][col4] = *(const v4*)&Bb[(size_t)c * HW + jb + col4];
        }
        __syncthreads();
        v4 a0 = {0,0,0,0}, a1 = {0,0,0,0}, a2 = {0,0,0,0}, a3 = {0,0,0,0};
        v4 a4 = {0,0,0,0}, a5 = {0,0,0,0}, a6 = {0,0,0,0}, a7 = {0,0,0,0};
#pragma unroll 4
        for (int c = 0; c < C2; ++c) {
            float av = Ab[(size_t)c * HW + ci];      // coalesced; zero-padded past ni
            const v4* br = (const v4*)&Bs[c][0];     // wave-uniform address
            a0 += br[0] * av;  a1 += br[1] * av;
            a2 += br[2] * av;  a3 += br[3] * av;
            a4 += br[4] * av;  a5 += br[5] * av;
            a6 += br[6] * av;  a7 += br[7] * av;
        }
        int lim = j1 - jb;                           // tail guard (padded cols are zeros)
#define SEL(Q) { \
        if (Q*4+0 < lim && a##Q.x > best) { best = a##Q.x; bestjj = jb + Q*4+0; } \
        if (Q*4+1 < lim && a##Q.y > best) { best = a##Q.y; bestjj = jb + Q*4+1; } \
        if (Q*4+2 < lim && a##Q.z > best) { best = a##Q.z; bestjj = jb + Q*4+2; } \
        if (Q*4+3 < lim && a##Q.w > best) { best = a##Q.w; bestjj = jb + Q*4+3; } }
        SEL(0) SEL(1) SEL(2) SEL(3) SEL(4) SEL(5) SEL(6) SEL(7)
#undef SEL
    }
    if (ci < ni && bestjj >= 0) {
        unsigned long long key = ((unsigned long long)ordf(best) << 32) |
                                 (unsigned long long)(~(unsigned int)bestjj);
        atomicMax(&amax[(size_t)b * HW + ilist[ci]], key);   // keyed by ORIGINAL position
    }
}

// ---------------- kernel 4: fused epilogue (copy + decode + gather) -------
// out channels [0,128): passthrough copy of x (float4).
// out channels [128,192): shift = former at argmax j (0 where !flag).
__global__ void epilogue_kernel(const float4* __restrict__ x4, const float* __restrict__ x,
                                const int* __restrict__ mask,
                                const unsigned long long* __restrict__ amax,
                                const int* __restrict__ jlist, float4* __restrict__ out4) {
    const int q = HW / 4;                            // 2304
    int t = blockIdx.x * blockDim.x + threadIdx.x;   // 0 .. 2*192*q-1
    if (t >= 2 * 192 * q) return;
    int pos4 = t % q;
    int c = (t / q) % 192;
    int b = t / (192 * q);
    if (c < 128) {
        out4[t] = x4[((size_t)b * 128 + c) * q + pos4];
    } else {
        float4 v = make_float4(0.f, 0.f, 0.f, 0.f);
        float* vp = &v.x;
        int pos = pos4 * 4;
        const float* xf = x + (size_t)(b * 128 + (c - 128)) * HW;
#pragma unroll
        for (int k = 0; k < 4; k++) {
            int p = pos + k;
            if (mask[p] >= 1) {
                unsigned long long key = amax[(size_t)b * HW + p];
                int j = 0;                           // nj==0 -> argmax of all-NEG row = 0
                if (key != 0ull) j = jlist[(int)(~(unsigned int)key)];
                vp[k] = xf[j];
            }
        }
        out4[t] = v;
    }
}

extern "C" void kernel_launch(void* const* d_in, const int* in_sizes, int n_in,
                              void* d_out, int out_size, void* d_ws, size_t ws_size,
                              hipStream_t stream) {
    const float* x = (const float*)d_in[0];
    const int* mask = (const int*)d_in[1];
    float4* out4 = (float4*)d_out;

    // workspace: counts(0) | ilist(128) | jlist(+36864) | amax(+36864)
    //            | amatT(+147456) | bmatT(+4718592)   (all 128B-aligned)
    char* ws = (char*)d_ws;
    int*   counts = (int*)ws;
    int*   ilist  = (int*)(ws + 128);
    int*   jlist  = (int*)(ws + 128 + 36864);
    unsigned long long* amax = (unsigned long long*)(ws + 128 + 2 * 36864);      // 147456 B
    float* amatT  = (float*)(ws + 128 + 2 * 36864 + 147456);                     // 4718592 B
    float* bmatT  = (float*)(ws + 128 + 2 * 36864 + 147456 + 4718592);           // 4718592 B

    // 1) compaction
    compact_kernel<<<1, 256, 0, stream>>>(mask, ilist, jlist, counts);
    // 2) transposed compacted A + normalized B (+ amax zeroing)
    buildab_kernel<<<(4 * HW + 255) / 256, 256, 0, stream>>>(x, ilist, jlist, counts,
                                                             amatT, bmatT, amax);
    // 3) broadcast-B GEMM + argmax: grid (i-blocks, j-chunks, batch)
    {
        dim3 grid(HW / 256, NJC, 2);                 // dead i-blocks exit early
        gemm_argmax_kernel<<<grid, 256, 0, stream>>>(amatT, bmatT, ilist, counts, amax);
    }
    // 4) fused copy + decode + gather
    {
        int n = 2 * 192 * (HW / 4);
        epilogue_kernel<<<(n + 255) / 256, 256, 0, stream>>>((const float4*)x, x, mask, amax, jlist, out4);
    }
}